// Round 6
// baseline (844.789 us; speedup 1.0000x reference)
//
#include <hip/hip_runtime.h>

static constexpr int   N_NODES = 50000;
static constexpr int   N_EDGES = 600000;
static constexpr int   D       = 128;
static constexpr float ALPHA   = 0.1f;
static constexpr float BETA    = 0.22314355131420976f;  // log(1.25)
static constexpr float OMB     = 1.0f - BETA;           // (1-beta)

static constexpr int SCAN_TPB    = 256;
static constexpr int SCAN_BLOCKS = (N_NODES + SCAN_TPB - 1) / SCAN_TPB;  // 196

// ---------------- degree histogram (int atomics) ----------------
__global__ void deg_kernel(const int* __restrict__ dst, int* __restrict__ deg) {
    int e = blockIdx.x * blockDim.x + threadIdx.x;
    if (e < N_EDGES) atomicAdd(&deg[dst[e]], 1);
}

// ---------------- scan phase 1: per-block reduction ----------------
__global__ __launch_bounds__(SCAN_TPB) void partial_kernel(const int* __restrict__ deg,
                                                           int* __restrict__ blocksum) {
    __shared__ int sh[SCAN_TPB];
    const int t = threadIdx.x;
    const int i = blockIdx.x * SCAN_TPB + t;
    sh[t] = (i < N_NODES) ? deg[i] : 0;
    __syncthreads();
    for (int off = SCAN_TPB / 2; off > 0; off >>= 1) {
        if (t < off) sh[t] += sh[t + off];
        __syncthreads();
    }
    if (t == 0) blocksum[blockIdx.x] = sh[0];
}

// ---------------- scan phase 2: exclusive scan of block sums (1 block) ----------------
__global__ __launch_bounds__(SCAN_TPB) void scanblock_kernel(int* __restrict__ blocksum) {
    __shared__ int sh[SCAN_TPB];
    const int t = threadIdx.x;
    int v = (t < SCAN_BLOCKS) ? blocksum[t] : 0;
    sh[t] = v;
    __syncthreads();
    for (int off = 1; off < SCAN_TPB; off <<= 1) {
        int u = (t >= off) ? sh[t - off] : 0;
        __syncthreads();
        sh[t] += u;
        __syncthreads();
    }
    if (t < SCAN_BLOCKS) blocksum[t] = sh[t] - v;   // exclusive
}

// ---------------- scan phase 3: per-block exclusive scan + offset; fused norm ----------------
__global__ __launch_bounds__(SCAN_TPB) void finalscan_kernel(
    const int* __restrict__ deg, const int* __restrict__ blocksum,
    int* __restrict__ row_start, int* __restrict__ cursor, float* __restrict__ norm) {
    __shared__ int sh[SCAN_TPB];
    const int t = threadIdx.x;
    const int i = blockIdx.x * SCAN_TPB + t;
    int d = (i < N_NODES) ? deg[i] : 0;
    sh[t] = d;
    __syncthreads();
    for (int off = 1; off < SCAN_TPB; off <<= 1) {
        int u = (t >= off) ? sh[t - off] : 0;
        __syncthreads();
        sh[t] += u;
        __syncthreads();
    }
    if (i < N_NODES) {
        int pos = blocksum[blockIdx.x] + sh[t] - d;   // exclusive prefix
        row_start[i] = pos;
        cursor[i]    = pos;
        norm[i]      = rsqrtf(fmaxf((float)d, 1.0f));
    }
}

// ---------------- CSR fill: csr[pos] = src, pos = cursor[dst]++ ----------------
__global__ void fill_kernel(const int* __restrict__ src, const int* __restrict__ dst,
                            int* __restrict__ cursor, int* __restrict__ csr) {
    int e = blockIdx.x * blockDim.x + threadIdx.x;
    if (e < N_EDGES) {
        int d   = dst[e];
        int pos = atomicAdd(&cursor[d], 1);
        if (pos >= 0 && pos < N_EDGES) csr[pos] = src[e];  // defensive bound
    }
}

// ---------------- gather: agg[n] = sum_{e: dst=n} feat[src_e] * norm[src_e] ----------------
// one wave (64 lanes) per node; each lane owns 2 columns (float2); 4-edge unroll
__global__ __launch_bounds__(256) void gather_kernel(
    const float* __restrict__ feat, const int* __restrict__ csr,
    const int* __restrict__ row_start, const int* __restrict__ deg,
    const float* __restrict__ norm, float* __restrict__ agg) {
    const int node = blockIdx.x * 4 + (threadIdx.x >> 6);
    const int lane = threadIdx.x & 63;
    if (node >= N_NODES) return;
    const int base = row_start[node];
    const int cnt  = deg[node];
    float2 acc = make_float2(0.f, 0.f);
    int j = 0;
    for (; j + 3 < cnt; j += 4) {
        int s0 = csr[base + j];
        int s1 = csr[base + j + 1];
        int s2 = csr[base + j + 2];
        int s3 = csr[base + j + 3];
        float n0 = norm[s0], n1 = norm[s1], n2 = norm[s2], n3 = norm[s3];
        float2 v0 = *reinterpret_cast<const float2*>(feat + (size_t)s0 * D + lane * 2);
        float2 v1 = *reinterpret_cast<const float2*>(feat + (size_t)s1 * D + lane * 2);
        float2 v2 = *reinterpret_cast<const float2*>(feat + (size_t)s2 * D + lane * 2);
        float2 v3 = *reinterpret_cast<const float2*>(feat + (size_t)s3 * D + lane * 2);
        acc.x += v0.x * n0 + v1.x * n1 + v2.x * n2 + v3.x * n3;
        acc.y += v0.y * n0 + v1.y * n1 + v2.y * n2 + v3.y * n3;
    }
    for (; j < cnt; ++j) {
        int s = csr[base + j];
        float n = norm[s];
        float2 v = *reinterpret_cast<const float2*>(feat + (size_t)s * D + lane * 2);
        acc.x += v.x * n;
        acc.y += v.y * n;
    }
    *reinterpret_cast<float2*>(agg + (size_t)node * D + lane * 2) = acc;
}

// ---------------- fused epilogue + GEMM, register-blocked 4x4 ----------------
// 32 rows/block; W streamed through LDS in two 64-row chunks (32 KB buffer).
// thread (t): cols c0..c0+3 (c0=(t&31)*4), rows r0..r0+3 (r0=(t>>5)*4).
static constexpr int TM = 32;   // rows per block

__global__ __launch_bounds__(256) void final_kernel(
    const float* __restrict__ feat_0,
    const float* __restrict__ W,
    const float* __restrict__ bias,
    const float* __restrict__ norm,
    float* __restrict__ out)   // enters holding agg, exits holding rst
{
    __shared__ float w_sh[64 * D];   // 32 KB: half of W (64 k-rows)
    __shared__ float h_sh[TM * D];   // 16 KB

    const int t    = threadIdx.x;
    const int row0 = blockIdx.x * TM;

    // build h tile: TM*D = 4096 floats / 256 threads = 4 float4 each (coalesced)
    #pragma unroll
    for (int i = 0; i < 4; ++i) {
        int idx  = (i * 256 + t) * 4;     // 0..4092
        int r    = idx >> 7;
        int c    = idx & 127;
        int node = row0 + r;
        float4 h = make_float4(0.f, 0.f, 0.f, 0.f);
        if (node < N_NODES) {
            float nm = norm[node] * (1.0f - ALPHA);
            float4 a  = *reinterpret_cast<const float4*>(out    + (size_t)node * D + c);
            float4 f0 = *reinterpret_cast<const float4*>(feat_0 + (size_t)node * D + c);
            h.x = a.x * nm + f0.x * ALPHA;
            h.y = a.y * nm + f0.y * ALPHA;
            h.z = a.z * nm + f0.z * ALPHA;
            h.w = a.w * nm + f0.w * ALPHA;
        }
        *reinterpret_cast<float4*>(&h_sh[idx]) = h;
    }

    const int c0 = (t & 31) * 4;
    const int r0 = (t >> 5) * 4;

    float4 acc[4];   // acc[j] = row r0+j, cols c0..c0+3
    #pragma unroll
    for (int j = 0; j < 4; ++j) acc[j] = make_float4(0.f, 0.f, 0.f, 0.f);

    #pragma unroll
    for (int half = 0; half < 2; ++half) {
        __syncthreads();  // phase 0: h_sh complete; phase 1: w_sh no longer read
        // load 64 k-rows of W: 8192 floats / 256 threads = 8 float4 each (coalesced)
        #pragma unroll
        for (int i = 0; i < 8; ++i) {
            int idx = (i * 256 + t) * 4;  // 0..8188
            *reinterpret_cast<float4*>(&w_sh[idx]) =
                *reinterpret_cast<const float4*>(W + (size_t)half * 64 * D + idx);
        }
        __syncthreads();

        for (int kk = 0; kk < 64; kk += 4) {
            const int kb = half * 64 + kk;
            // h fragments: broadcast reads (lanes 0-31 same addr)
            float4 hv[4];
            #pragma unroll
            for (int j = 0; j < 4; ++j)
                hv[j] = *reinterpret_cast<const float4*>(&h_sh[(r0 + j) * D + kb]);
            // w fragments: lane-contiguous b128
            float4 wv[4];
            #pragma unroll
            for (int ki = 0; ki < 4; ++ki)
                wv[ki] = *reinterpret_cast<const float4*>(&w_sh[(kk + ki) * D + c0]);
            #pragma unroll
            for (int ki = 0; ki < 4; ++ki) {
                #pragma unroll
                for (int j = 0; j < 4; ++j) {
                    float hj = (ki == 0) ? hv[j].x : (ki == 1) ? hv[j].y
                             : (ki == 2) ? hv[j].z : hv[j].w;
                    acc[j].x += hj * wv[ki].x;
                    acc[j].y += hj * wv[ki].y;
                    acc[j].z += hj * wv[ki].z;
                    acc[j].w += hj * wv[ki].w;
                }
            }
        }
    }

    const float4 b4 = *reinterpret_cast<const float4*>(bias + c0);
    #pragma unroll
    for (int j = 0; j < 4; ++j) {
        int node = row0 + r0 + j;
        if (node < N_NODES) {
            float4 h = *reinterpret_cast<const float4*>(&h_sh[(r0 + j) * D + c0]);
            float4 o;
            o.x = OMB * h.x + BETA * acc[j].x + b4.x;
            o.y = OMB * h.y + BETA * acc[j].y + b4.y;
            o.z = OMB * h.z + BETA * acc[j].z + b4.z;
            o.w = OMB * h.w + BETA * acc[j].w + b4.w;
            *reinterpret_cast<float4*>(out + (size_t)node * D + c0) = o;
        }
    }
}

extern "C" void kernel_launch(void* const* d_in, const int* in_sizes, int n_in,
                              void* d_out, int out_size, void* d_ws, size_t ws_size,
                              hipStream_t stream) {
    const float* feat   = (const float*)d_in[0];
    const float* feat_0 = (const float*)d_in[1];
    const float* W      = (const float*)d_in[2];
    const float* bias   = (const float*)d_in[3];
    const int*   src    = (const int*)d_in[4];
    const int*   dst    = (const int*)d_in[5];
    float*       out    = (float*)d_out;

    // workspace layout
    char* ws = (char*)d_ws;
    int*   deg       = (int*)ws;    ws += (size_t)N_NODES * 4;
    float* norm      = (float*)ws;  ws += (size_t)N_NODES * 4;
    int*   row_start = (int*)ws;    ws += (size_t)N_NODES * 4;
    int*   cursor    = (int*)ws;    ws += (size_t)N_NODES * 4;
    int*   blocksum  = (int*)ws;    ws += (size_t)SCAN_TPB * 4;
    int*   csr       = (int*)ws;    ws += (size_t)N_EDGES * 4;

    hipMemsetAsync(deg, 0, (size_t)N_NODES * sizeof(int), stream);

    deg_kernel<<<(N_EDGES + 255) / 256, 256, 0, stream>>>(dst, deg);

    partial_kernel  <<<SCAN_BLOCKS, SCAN_TPB, 0, stream>>>(deg, blocksum);
    scanblock_kernel<<<1,           SCAN_TPB, 0, stream>>>(blocksum);
    finalscan_kernel<<<SCAN_BLOCKS, SCAN_TPB, 0, stream>>>(deg, blocksum,
                                                           row_start, cursor, norm);

    fill_kernel<<<(N_EDGES + 255) / 256, 256, 0, stream>>>(src, dst, cursor, csr);
    gather_kernel<<<(N_NODES + 3) / 4, 256, 0, stream>>>(feat, csr, row_start, deg, norm, out);
    final_kernel<<<(N_NODES + TM - 1) / TM, 256, 0, stream>>>(feat_0, W, bias, norm, out);
}

// Round 7
// 233.563 us; speedup vs baseline: 3.6170x; 3.6170x over previous
//
#include <hip/hip_runtime.h>

static constexpr int   N_NODES = 50000;
static constexpr int   N_EDGES = 600000;
static constexpr int   D       = 128;
static constexpr float ALPHA   = 0.1f;
static constexpr float BETA    = 0.22314355131420976f;  // log(1.25)
static constexpr float OMB     = 1.0f - BETA;           // (1-beta)

static constexpr int SCAN_TPB    = 256;
static constexpr int SCAN_BLOCKS = (N_NODES + SCAN_TPB - 1) / SCAN_TPB;  // 196

// ---------------- degree histogram (int atomics) ----------------
__global__ void deg_kernel(const int* __restrict__ dst, int* __restrict__ deg) {
    int e = blockIdx.x * blockDim.x + threadIdx.x;
    if (e < N_EDGES) atomicAdd(&deg[dst[e]], 1);
}

// ---------------- scan phase 1: per-block reduction ----------------
__global__ __launch_bounds__(SCAN_TPB) void partial_kernel(const int* __restrict__ deg,
                                                           int* __restrict__ blocksum) {
    __shared__ int sh[SCAN_TPB];
    const int t = threadIdx.x;
    const int i = blockIdx.x * SCAN_TPB + t;
    sh[t] = (i < N_NODES) ? deg[i] : 0;
    __syncthreads();
    for (int off = SCAN_TPB / 2; off > 0; off >>= 1) {
        if (t < off) sh[t] += sh[t + off];
        __syncthreads();
    }
    if (t == 0) blocksum[blockIdx.x] = sh[0];
}

// ---------------- scan phase 2: exclusive scan of block sums (1 block) ----------------
__global__ __launch_bounds__(SCAN_TPB) void scanblock_kernel(int* __restrict__ blocksum) {
    __shared__ int sh[SCAN_TPB];
    const int t = threadIdx.x;
    int v = (t < SCAN_BLOCKS) ? blocksum[t] : 0;
    sh[t] = v;
    __syncthreads();
    for (int off = 1; off < SCAN_TPB; off <<= 1) {
        int u = (t >= off) ? sh[t - off] : 0;
        __syncthreads();
        sh[t] += u;
        __syncthreads();
    }
    if (t < SCAN_BLOCKS) blocksum[t] = sh[t] - v;   // exclusive
}

// ---------------- scan phase 3: per-block exclusive scan + offset; fused norm ----------------
__global__ __launch_bounds__(SCAN_TPB) void finalscan_kernel(
    const int* __restrict__ deg, const int* __restrict__ blocksum,
    int* __restrict__ row_start, int* __restrict__ cursor, float* __restrict__ norm) {
    __shared__ int sh[SCAN_TPB];
    const int t = threadIdx.x;
    const int i = blockIdx.x * SCAN_TPB + t;
    int d = (i < N_NODES) ? deg[i] : 0;
    sh[t] = d;
    __syncthreads();
    for (int off = 1; off < SCAN_TPB; off <<= 1) {
        int u = (t >= off) ? sh[t - off] : 0;
        __syncthreads();
        sh[t] += u;
        __syncthreads();
    }
    if (i < N_NODES) {
        int pos = blocksum[blockIdx.x] + sh[t] - d;   // exclusive prefix
        row_start[i] = pos;
        cursor[i]    = pos;
        norm[i]      = rsqrtf(fmaxf((float)d, 1.0f));
    }
}

// ---------------- CSR fill: csr[pos] = src, pos = cursor[dst]++ ----------------
__global__ void fill_kernel(const int* __restrict__ src, const int* __restrict__ dst,
                            int* __restrict__ cursor, int* __restrict__ csr) {
    int e = blockIdx.x * blockDim.x + threadIdx.x;
    if (e < N_EDGES) {
        int d   = dst[e];
        int pos = atomicAdd(&cursor[d], 1);
        if (pos >= 0 && pos < N_EDGES) csr[pos] = src[e];  // defensive bound
    }
}

// ---------------- gather: agg[n] = sum_{e: dst=n} feat[src_e] * norm[src_e] ----------------
// one wave (64 lanes) per node; each lane owns 2 columns (float2); 4-edge unroll
__global__ __launch_bounds__(256) void gather_kernel(
    const float* __restrict__ feat, const int* __restrict__ csr,
    const int* __restrict__ row_start, const int* __restrict__ deg,
    const float* __restrict__ norm, float* __restrict__ agg) {
    const int node = blockIdx.x * 4 + (threadIdx.x >> 6);
    const int lane = threadIdx.x & 63;
    if (node >= N_NODES) return;
    const int base = row_start[node];
    const int cnt  = deg[node];
    float2 acc = make_float2(0.f, 0.f);
    int j = 0;
    for (; j + 3 < cnt; j += 4) {
        int s0 = csr[base + j];
        int s1 = csr[base + j + 1];
        int s2 = csr[base + j + 2];
        int s3 = csr[base + j + 3];
        float n0 = norm[s0], n1 = norm[s1], n2 = norm[s2], n3 = norm[s3];
        float2 v0 = *reinterpret_cast<const float2*>(feat + (size_t)s0 * D + lane * 2);
        float2 v1 = *reinterpret_cast<const float2*>(feat + (size_t)s1 * D + lane * 2);
        float2 v2 = *reinterpret_cast<const float2*>(feat + (size_t)s2 * D + lane * 2);
        float2 v3 = *reinterpret_cast<const float2*>(feat + (size_t)s3 * D + lane * 2);
        acc.x += v0.x * n0 + v1.x * n1 + v2.x * n2 + v3.x * n3;
        acc.y += v0.y * n0 + v1.y * n1 + v2.y * n2 + v3.y * n3;
    }
    for (; j < cnt; ++j) {
        int s = csr[base + j];
        float n = norm[s];
        float2 v = *reinterpret_cast<const float2*>(feat + (size_t)s * D + lane * 2);
        acc.x += v.x * n;
        acc.y += v.y * n;
    }
    *reinterpret_cast<float2*>(agg + (size_t)node * D + lane * 2) = acc;
}

// ---------------- fused epilogue + GEMM, register-blocked 4x4 ----------------
// 32 rows/block; W streamed through LDS in two 64-row chunks (32 KB buffer).
// thread (t): cols c0..c0+3 (c0=(t&31)*4), rows r0..r0+3 (r0=(t>>5)*4).
// __launch_bounds__(256,4): cap 128 VGPR; #pragma unroll 1 on the k-loop
// prevents the full-unroll load-hoist that spilled to scratch in round 6
// (VGPR=256, 1.8 GB scratch traffic).
static constexpr int TM = 32;   // rows per block

__global__ __launch_bounds__(256, 4) void final_kernel(
    const float* __restrict__ feat_0,
    const float* __restrict__ W,
    const float* __restrict__ bias,
    const float* __restrict__ norm,
    float* __restrict__ out)   // enters holding agg, exits holding rst
{
    __shared__ float w_sh[64 * D];   // 32 KB: half of W (64 k-rows)
    __shared__ float h_sh[TM * D];   // 16 KB

    const int t    = threadIdx.x;
    const int row0 = blockIdx.x * TM;

    // build h tile: TM*D = 4096 floats / 256 threads = 4 float4 each (coalesced)
    #pragma unroll
    for (int i = 0; i < 4; ++i) {
        int idx  = (i * 256 + t) * 4;     // 0..4092
        int r    = idx >> 7;
        int c    = idx & 127;
        int node = row0 + r;
        float4 h = make_float4(0.f, 0.f, 0.f, 0.f);
        if (node < N_NODES) {
            float nm = norm[node] * (1.0f - ALPHA);
            float4 a  = *reinterpret_cast<const float4*>(out    + (size_t)node * D + c);
            float4 f0 = *reinterpret_cast<const float4*>(feat_0 + (size_t)node * D + c);
            h.x = a.x * nm + f0.x * ALPHA;
            h.y = a.y * nm + f0.y * ALPHA;
            h.z = a.z * nm + f0.z * ALPHA;
            h.w = a.w * nm + f0.w * ALPHA;
        }
        *reinterpret_cast<float4*>(&h_sh[idx]) = h;
    }

    const int c0 = (t & 31) * 4;
    const int r0 = (t >> 5) * 4;

    float4 acc[4];   // acc[j] = row r0+j, cols c0..c0+3
    #pragma unroll
    for (int j = 0; j < 4; ++j) acc[j] = make_float4(0.f, 0.f, 0.f, 0.f);

    #pragma unroll 1
    for (int half = 0; half < 2; ++half) {
        __syncthreads();  // phase 0: h_sh complete; phase 1: w_sh no longer read
        // load 64 k-rows of W: 8192 floats / 256 threads = 8 float4 each (coalesced)
        #pragma unroll
        for (int i = 0; i < 8; ++i) {
            int idx = (i * 256 + t) * 4;  // 0..8188
            *reinterpret_cast<float4*>(&w_sh[idx]) =
                *reinterpret_cast<const float4*>(W + (size_t)half * 64 * D + idx);
        }
        __syncthreads();

        #pragma unroll 1
        for (int kk = 0; kk < 64; kk += 4) {
            const int kb = half * 64 + kk;
            // h fragments: broadcast reads (lanes 0-31 same addr)
            float4 hv[4];
            #pragma unroll
            for (int j = 0; j < 4; ++j)
                hv[j] = *reinterpret_cast<const float4*>(&h_sh[(r0 + j) * D + kb]);
            // w fragments: lane-contiguous b128
            float4 wv[4];
            #pragma unroll
            for (int ki = 0; ki < 4; ++ki)
                wv[ki] = *reinterpret_cast<const float4*>(&w_sh[(kk + ki) * D + c0]);
            #pragma unroll
            for (int ki = 0; ki < 4; ++ki) {
                #pragma unroll
                for (int j = 0; j < 4; ++j) {
                    float hj = (ki == 0) ? hv[j].x : (ki == 1) ? hv[j].y
                             : (ki == 2) ? hv[j].z : hv[j].w;
                    acc[j].x += hj * wv[ki].x;
                    acc[j].y += hj * wv[ki].y;
                    acc[j].z += hj * wv[ki].z;
                    acc[j].w += hj * wv[ki].w;
                }
            }
        }
    }

    const float4 b4 = *reinterpret_cast<const float4*>(bias + c0);
    #pragma unroll
    for (int j = 0; j < 4; ++j) {
        int node = row0 + r0 + j;
        if (node < N_NODES) {
            float4 h = *reinterpret_cast<const float4*>(&h_sh[(r0 + j) * D + c0]);
            float4 o;
            o.x = OMB * h.x + BETA * acc[j].x + b4.x;
            o.y = OMB * h.y + BETA * acc[j].y + b4.y;
            o.z = OMB * h.z + BETA * acc[j].z + b4.z;
            o.w = OMB * h.w + BETA * acc[j].w + b4.w;
            *reinterpret_cast<float4*>(out + (size_t)node * D + c0) = o;
        }
    }
}

extern "C" void kernel_launch(void* const* d_in, const int* in_sizes, int n_in,
                              void* d_out, int out_size, void* d_ws, size_t ws_size,
                              hipStream_t stream) {
    const float* feat   = (const float*)d_in[0];
    const float* feat_0 = (const float*)d_in[1];
    const float* W      = (const float*)d_in[2];
    const float* bias   = (const float*)d_in[3];
    const int*   src    = (const int*)d_in[4];
    const int*   dst    = (const int*)d_in[5];
    float*       out    = (float*)d_out;

    // workspace layout
    char* ws = (char*)d_ws;
    int*   deg       = (int*)ws;    ws += (size_t)N_NODES * 4;
    float* norm      = (float*)ws;  ws += (size_t)N_NODES * 4;
    int*   row_start = (int*)ws;    ws += (size_t)N_NODES * 4;
    int*   cursor    = (int*)ws;    ws += (size_t)N_NODES * 4;
    int*   blocksum  = (int*)ws;    ws += (size_t)SCAN_TPB * 4;
    int*   csr       = (int*)ws;    ws += (size_t)N_EDGES * 4;

    hipMemsetAsync(deg, 0, (size_t)N_NODES * sizeof(int), stream);

    deg_kernel<<<(N_EDGES + 255) / 256, 256, 0, stream>>>(dst, deg);

    partial_kernel  <<<SCAN_BLOCKS, SCAN_TPB, 0, stream>>>(deg, blocksum);
    scanblock_kernel<<<1,           SCAN_TPB, 0, stream>>>(blocksum);
    finalscan_kernel<<<SCAN_BLOCKS, SCAN_TPB, 0, stream>>>(deg, blocksum,
                                                           row_start, cursor, norm);

    fill_kernel<<<(N_EDGES + 255) / 256, 256, 0, stream>>>(src, dst, cursor, csr);
    gather_kernel<<<(N_NODES + 3) / 4, 256, 0, stream>>>(feat, csr, row_start, deg, norm, out);
    final_kernel<<<(N_NODES + TM - 1) / TM, 256, 0, stream>>>(feat_0, W, bias, norm, out);
}